// Round 4
// baseline (185.963 us; speedup 1.0000x reference)
//
#include <hip/hip_runtime.h>
#include <hip/hip_bf16.h>

// B=2, S=2048, D=1024, H=16, HD=64.  out = proj(attn(qkv(x))), fp32 I/O,
// bf16 MFMA internally.
//
// R15 (attn8): 32 q/wave kept from attn7 (halves LDS-read traffic/query vs
// attn6), but back to 1024 fine-grained blocks: 128 threads (2 waves x 32 q
// = 64 queries/block).  attn7's regression (41 vs 30 us) was static-schedule
// load imbalance: 512 blocks on 512 slots, heavy/light pairing not honored
// by the dispatcher.  attn8 makes every CU's block-quadruple sum-constant:
// qb remap over g=bx>>5 with quadruples {31-g0, 16+g0, 15-g0, g0} -> 66
// chunk-units per CU under XCD round-robin slot fill, bounded skew otherwise.
// Per-CU ds_read drops to ~2.1 MB (~10 us floor) vs attn6's 4.2 MB.

typedef __attribute__((ext_vector_type(8))) short short8;
typedef __attribute__((ext_vector_type(4))) float float4v;

#define S_LEN 2048
#define NHEAD 16
#define HDIM  64
#define DMODEL 1024

__device__ __forceinline__ unsigned short f2bf(float f) {
    union { float f; unsigned u; } v; v.f = f;
    unsigned r = v.u + 0x7FFF + ((v.u >> 16) & 1);   // RNE
    return (unsigned short)(r >> 16);
}

__device__ __forceinline__ unsigned fbits_rn(float f) {  // bits+0x8000: RN pack
    union { float f; unsigned u; } v; v.f = f;
    return v.u + 0x8000u;
}

__device__ __forceinline__ void async16(const void* g, const void* l) {
    __builtin_amdgcn_global_load_lds(
        (const __attribute__((address_space(1))) unsigned int*)g,
        (__attribute__((address_space(3))) unsigned int*)l, 16, 0, 0);
}

// ---------------------------------------------------------------------------
__global__ void f32_to_bf16_v4(const float4* __restrict__ in,
                               ushort4* __restrict__ out, int n4) {
    int i = blockIdx.x * blockDim.x + threadIdx.x;
    if (i < n4) {
        float4 v = in[i];
        ushort4 o;
        o.x = f2bf(v.x); o.y = f2bf(v.y); o.z = f2bf(v.z); o.w = f2bf(v.w);
        out[i] = o;
    }
}

// Both weight matrices, one launch. in[K][N] fp32 -> out[N][K] bf16.
__global__ __launch_bounds__(256) void w_transpose_bf16(
    const float* __restrict__ Wqkv, const float* __restrict__ Wproj,
    unsigned short* __restrict__ outQ, unsigned short* __restrict__ outP) {
    __shared__ float t[64][65];
    const float* in; unsigned short* out; int N, bxl;
    if (blockIdx.x < 48) { in = Wqkv;  out = outQ; N = 3072; bxl = blockIdx.x; }
    else                 { in = Wproj; out = outP; N = 1024; bxl = blockIdx.x - 48; }
    const int K = 1024;
    const int kb = blockIdx.y * 64, nb = bxl * 64;
    const int tid = threadIdx.x;
    const int r0 = tid >> 4, c0 = (tid & 15) * 4;
#pragma unroll
    for (int g = 0; g < 4; g++) {
        float4 v = *(const float4*)(in + (size_t)(kb + g * 16 + r0) * N + nb + c0);
        t[g * 16 + r0][c0 + 0] = v.x; t[g * 16 + r0][c0 + 1] = v.y;
        t[g * 16 + r0][c0 + 2] = v.z; t[g * 16 + r0][c0 + 3] = v.w;
    }
    __syncthreads();
#pragma unroll
    for (int g = 0; g < 4; g++) {
        int n = g * 16 + r0;
        ushort4 o;
        o.x = f2bf(t[c0 + 0][n]); o.y = f2bf(t[c0 + 1][n]);
        o.z = f2bf(t[c0 + 2][n]); o.w = f2bf(t[c0 + 3][n]);
        *(ushort4*)(out + (size_t)(nb + n) * K + kb + c0) = o;
    }
}

// V [bh][s][64] -> Vp [bh][chunk][nt][kk][lane][8]  (fragment-major).
// Fragment semantics (R3-verified): vf[nt][kk] lane(quad,l16), short j:
//   key = (kk*2 + (j>>2))*16 + quad*4 + (j&3),  hd = nt*16 + l16.
__global__ __launch_bounds__(256) void v_pack(
    const unsigned short* __restrict__ V, unsigned short* __restrict__ Vp) {
    __shared__ unsigned short t[64 * 68];
    const int bh = blockIdx.y;
    const int c0 = blockIdx.x;          // 64-key chunk
    const int s0 = c0 * 64;
    const int tid = threadIdx.x;
    const int r = tid >> 2, c4 = tid & 3;
    const size_t base = (size_t)bh * S_LEN * HDIM;
    union { uint4 v[2]; unsigned short u[16]; } d;
    const unsigned short* src = V + base + (size_t)(s0 + r) * HDIM + c4 * 16;
    d.v[0] = *(const uint4*)(src);
    d.v[1] = *(const uint4*)(src + 8);
#pragma unroll
    for (int j = 0; j < 16; j++) t[r * 68 + c4 * 16 + j] = d.u[j];  // t[key][hd]
    __syncthreads();
    // 512 16B pieces, 2 per thread (consecutive lanes -> 32B/thread store)
    unsigned short* outb = Vp + ((size_t)(bh * 32 + c0)) * 4096;
#pragma unroll
    for (int pi = 0; pi < 2; pi++) {
        const int p = tid * 2 + pi;
        const int lane = p & 63, kk = (p >> 6) & 1, nt = p >> 7;
        const int q = lane >> 4, l = lane & 15;
        union { ushort4 v[2]; unsigned short u[8]; } w;
#pragma unroll
        for (int j = 0; j < 8; j++) {
            const int key = (kk * 2 + (j >> 2)) * 16 + q * 4 + (j & 3);
            w.u[j] = t[key * 68 + nt * 16 + l];
        }
        unsigned short* po = outb + ((nt * 2 + kk) * 64 + lane) * 8;
        *(ushort4*)(po) = w.v[0];
        *(ushort4*)(po + 4) = w.v[1];
    }
}

// ---------------------------------------------------------------------------
// QKV GEMM: C[M,3072] = A[M,1024]*Bt[3072,1024]^T + bias.  BK=64 (two 32-k
// half-planes).  Epilogue: pair-packed ds_write_b32 into 128x132 tile, then
// line-coalesced 16B stores: Q/V -> [bh][s][64], K -> Kp fragment-major.
// ---------------------------------------------------------------------------
#define QSCALE 0.18033688f   // 0.125 * log2(e), folded into Q

__global__ __launch_bounds__(256) void gemm_qkv_kernel(
    const unsigned short* __restrict__ A,
    const unsigned short* __restrict__ Bt,
    const float* __restrict__ bias,
    unsigned short* __restrict__ out_q,
    unsigned short* __restrict__ out_kp,
    unsigned short* __restrict__ out_v,
    int M, int N, int K)
{
    __shared__ unsigned short smem[128 * 132];
    unsigned short* As = smem;            // halves at +0, +4096 shorts
    unsigned short* Bs = smem + 8192;

    const int tid  = threadIdx.x;
    const int lane = tid & 63;
    const int wave = tid >> 6;
    const int quad = lane >> 4;
    const int l16  = lane & 15;

    const int m0 = blockIdx.y * 128;
    const int n0 = blockIdx.x * 128;
    const int wm = (wave >> 1) * 64;
    const int wn = (wave & 1) * 64;

    float4v acc[4][4];
#pragma unroll
    for (int i = 0; i < 4; i++)
#pragma unroll
        for (int j = 0; j < 4; j++) acc[i][j] = (float4v){0.f, 0.f, 0.f, 0.f};

    const int srow = lane >> 2;
    const int scol = (lane & 3) * 8;

    for (int k0 = 0; k0 < K; k0 += 64) {
        __syncthreads();
#pragma unroll
        for (int kk = 0; kk < 2; kk++)
#pragma unroll
            for (int it = 0; it < 2; it++) {
                const int rg = it * 64 + wave * 16;
                async16(A  + (size_t)(m0 + rg + srow) * K + k0 + kk * 32 + scol,
                        (const char*)(As + kk * 4096) + rg * 64);
                async16(Bt + (size_t)(n0 + rg + srow) * K + k0 + kk * 32 + scol,
                        (const char*)(Bs + kk * 4096) + rg * 64);
            }
        __syncthreads();

#pragma unroll
        for (int kk = 0; kk < 2; kk++) {
            short8 af[4], bf[4];
#pragma unroll
            for (int mt = 0; mt < 4; mt++)
                af[mt] = *(const short8*)(As + kk * 4096
                                          + (wm + mt * 16 + l16) * 32 + quad * 8);
#pragma unroll
            for (int nt = 0; nt < 4; nt++)
                bf[nt] = *(const short8*)(Bs + kk * 4096
                                          + (wn + nt * 16 + l16) * 32 + quad * 8);
#pragma unroll
            for (int mt = 0; mt < 4; mt++)
#pragma unroll
                for (int nt = 0; nt < 4; nt++)
                    acc[mt][nt] = __builtin_amdgcn_mfma_f32_16x16x32_bf16(
                        af[mt], bf[nt], acc[mt][nt], 0, 0, 0);
        }
    }

    // ---- epilogue: pair-packed b32 writes ----
    __syncthreads();
#pragma unroll
    for (int nt = 0; nt < 4; nt++) {
        const int col = n0 + wn + nt * 16 + l16;
        const float sc = ((col >> 10) == 0) ? QSCALE : 1.0f;
        const float bia = bias[col] * sc;
        const int cold = (wn + nt * 16 + l16) >> 1;
#pragma unroll
        for (int mt = 0; mt < 4; mt++)
#pragma unroll
            for (int r = 0; r < 4; r++) {
                unsigned fb = fbits_rn(acc[mt][nt][r] * sc + bia);
                unsigned fbp = (unsigned)__shfl_xor((int)fb, 1, 64);
                unsigned pd = (l16 & 1)
                    ? __builtin_amdgcn_perm(fb, fbp, 0x07060302)
                    : __builtin_amdgcn_perm(fbp, fb, 0x07060302);
                const int rowl = wm + mt * 16 + quad * 4 + r;
                *((unsigned*)smem + rowl * 66 + cold) = pd;
            }
    }
    __syncthreads();

    // ---- store phase: 16B pieces; K pieces go to fragment-major Kp ----
#pragma unroll
    for (int ps = 0; ps < 8; ps++) {
        const int row = ps * 16 + (tid >> 4);
        const int pc  = tid & 15;
        const int col0 = pc * 8;
        const int cb = n0 + (col0 >> 6) * 64;
        const int part = cb >> 10;
        const int hh = (cb & 1023) >> 6;           // head
        const int gr = m0 + row;
        const int b = gr >> 11, s = gr & 2047;
        const size_t bhI = (size_t)(b * NHEAD + hh);
        const unsigned short* pl = smem + row * 132 + col0;
        uint2 a = *(const uint2*)(pl);
        uint2 bb = *(const uint2*)(pl + 4);
        uint4 w; w.x = a.x; w.y = a.y; w.z = bb.x; w.w = bb.y;
        unsigned short* po;
        if (part == 1) {
            // Kp[bh][chunk=s>>6][kt=(s>>4)&3][h][lane=q*16+(s&15)][8]
            const int hd = col0 & 63;
            const int h = hd >> 5, q = (hd >> 3) & 3;
            po = out_kp + ((((bhI * 32 + (s >> 6)) * 4 + ((s >> 4) & 3)) * 2 + h)
                           * 64 + q * 16 + (s & 15)) * 8;
        } else {
            unsigned short* dst = (part == 0) ? out_q : out_v;
            po = dst + (bhI * S_LEN + s) * HDIM + (col0 & 63);
        }
        *(uint4*)po = w;
    }
}

// ---------------------------------------------------------------------------
// proj GEMM: out[M,1024] fp32 = ctx[M,1024]*Wt^T + bias.  64x128 tile, BK=64.
// ---------------------------------------------------------------------------
__global__ __launch_bounds__(256) void gemm_proj_kernel(
    const unsigned short* __restrict__ A,
    const unsigned short* __restrict__ Bt,
    const float* __restrict__ bias,
    float* __restrict__ out_f,
    int M, int N, int K)
{
    __shared__ unsigned short smem[12288];
    unsigned short* As = smem;               // halves at +0, +2048
    unsigned short* Bs = smem + 4096;        // halves at +0, +4096

    const int tid  = threadIdx.x;
    const int lane = tid & 63;
    const int wave = tid >> 6;
    const int quad = lane >> 4;
    const int l16  = lane & 15;

    const int m0 = blockIdx.y * 64;
    const int n0 = blockIdx.x * 128;
    const int wm = (wave >> 1) * 32;
    const int wn = (wave & 1) * 64;

    float4v acc[2][4];
#pragma unroll
    for (int i = 0; i < 2; i++)
#pragma unroll
        for (int j = 0; j < 4; j++) acc[i][j] = (float4v){0.f, 0.f, 0.f, 0.f};

    const int srow = lane >> 2;
    const int scol = (lane & 3) * 8;

    for (int k0 = 0; k0 < K; k0 += 64) {
        __syncthreads();
#pragma unroll
        for (int kk = 0; kk < 2; kk++) {
            async16(A + (size_t)(m0 + wave * 16 + srow) * K + k0 + kk * 32 + scol,
                    (const char*)(As + kk * 2048) + wave * 1024);
#pragma unroll
            for (int it = 0; it < 2; it++) {
                const int rg = it * 64 + wave * 16;
                async16(Bt + (size_t)(n0 + rg + srow) * K + k0 + kk * 32 + scol,
                        (const char*)(Bs + kk * 4096) + rg * 64);
            }
        }
        __syncthreads();

#pragma unroll
        for (int kk = 0; kk < 2; kk++) {
            short8 af[2], bf[4];
#pragma unroll
            for (int mt = 0; mt < 2; mt++)
                af[mt] = *(const short8*)(As + kk * 2048
                                          + (wm + mt * 16 + l16) * 32 + quad * 8);
#pragma unroll
            for (int nt = 0; nt < 4; nt++)
                bf[nt] = *(const short8*)(Bs + kk * 4096
                                          + (wn + nt * 16 + l16) * 32 + quad * 8);
#pragma unroll
            for (int mt = 0; mt < 2; mt++)
#pragma unroll
                for (int nt = 0; nt < 4; nt++)
                    acc[mt][nt] = __builtin_amdgcn_mfma_f32_16x16x32_bf16(
                        af[mt], bf[nt], acc[mt][nt], 0, 0, 0);
        }
    }

#pragma unroll
    for (int nt = 0; nt < 4; nt++) {
        const int col = n0 + wn + nt * 16 + l16;
        const float bia = bias[col];
#pragma unroll
        for (int mt = 0; mt < 2; mt++) {
            const int rowb = m0 + wm + mt * 16 + quad * 4;
#pragma unroll
            for (int r = 0; r < 4; r++)
                out_f[(size_t)(rowb + r) * N + col] = acc[mt][nt][r] + bia;
        }
    }
}

// ---------------------------------------------------------------------------
// Attention v8: 1024 blocks x 128 threads (2 waves x 32 queries = 64
// queries/block).  Per chunk the block stages K(8KB)+V(8KB) once into LDS
// (double-buffered, 32 KB); each wave's 16 ds_read_b128 feed 32 MFMAs.
// bh = bx&31 pins heads to XCDs.  qb remap over g=bx>>5: quadruples
// {31-g0, 16+g0, 15-g0, g0} so each CU's 4 resident blocks sum to 66
// chunk-units regardless of which quadruple it receives.
// All waves active in all chunks (no skip); mask only on last chunk.
// ---------------------------------------------------------------------------
__global__ __launch_bounds__(128, 2) void attn8_kernel(
    const unsigned short* __restrict__ Q,    // [bh][s][64] pre-scaled
    const unsigned short* __restrict__ Kp,   // [bh][32][4][2][64][8]
    const unsigned short* __restrict__ Vp,   // [bh][32][4][2][64][8]
    unsigned short* __restrict__ ctx)        // [B, S, H*64]
{
    __shared__ unsigned short lds[2][8192];  // [buf][K 0..4095 | V 4096..8191]

    const int tid  = threadIdx.x;            // 0..127
    const int lane = tid & 63;
    const int wave = tid >> 6;               // 0,1
    const int quad = lane >> 4;
    const int l16  = lane & 15;

    const int bx = blockIdx.x;
    const int bh = bx & 31;
    const int g  = bx >> 5;                  // 0..31
    const int g0 = g & 7, gt = g >> 3;
    // balanced quadruple remap: {31-g0, 16+g0, 15-g0, g0}
    const int qb = (gt == 0) ? (31 - g0)
                 : (gt == 1) ? (16 + g0)
                 : (gt == 2) ? (15 - g0)
                 :             g0;
    const int q0w = qb * 64 + wave * 32;     // this wave's first query
    const int nch = qb + 1;

    const size_t baseQ = (size_t)bh * S_LEN * HDIM;
    const unsigned short* kb_ = Kp + (size_t)bh * 32 * 4096;
    const unsigned short* vb_ = Vp + (size_t)bh * 32 * 4096;

    short8 qf[2][2];
#pragma unroll
    for (int qt = 0; qt < 2; qt++)
#pragma unroll
        for (int h = 0; h < 2; h++)
            qf[qt][h] = *(const short8*)(Q + baseQ
                                         + (size_t)(q0w + qt * 16 + l16) * HDIM
                                         + h * 32 + quad * 8);

    float4v o[2][4];
#pragma unroll
    for (int qt = 0; qt < 2; qt++)
#pragma unroll
        for (int nt = 0; nt < 4; nt++) o[qt][nt] = (float4v){0.f, 0.f, 0.f, 0.f};
    float lsa[2][4];
#pragma unroll
    for (int qt = 0; qt < 2; qt++)
#pragma unroll
        for (int kt = 0; kt < 4; kt++) lsa[qt][kt] = 0.f;

    // prologue: stage chunk 0 into buffer 0 (16 KB: 8 x async16 / thread)
    {
        unsigned short* sb = &lds[0][0];
#pragma unroll
        for (int i = 0; i < 4; i++) {
            async16(kb_ + (size_t)(i * 128 + tid) * 8,
                    sb + (i * 128 + wave * 64) * 8);
            async16(vb_ + (size_t)(i * 128 + tid) * 8,
                    sb + 4096 + (i * 128 + wave * 64) * 8);
        }
    }

    for (int c = 0; c < nch; c++) {
        __syncthreads();   // drains this wave's stage (implicit vmcnt(0));
                           // all waves' staged chunk c visible; buf c+1&1 free
        const unsigned short* lb = &lds[c & 1][0];
        const int kb0 = c * 64;

        // K fragments: linear conflict-free ds_read_b128
        short8 kf[4][2];
#pragma unroll
        for (int kt = 0; kt < 4; kt++)
#pragma unroll
            for (int h = 0; h < 2; h++)
                kf[kt][h] = *(const short8*)(lb + ((kt * 2 + h) * 64 + lane) * 8);

        // stage chunk c+1 into the other buffer (overlaps compute below)
        if (c + 1 < nch) {
            const unsigned short* kc = kb_ + (size_t)(c + 1) * 4096;
            const unsigned short* vc = vb_ + (size_t)(c + 1) * 4096;
            unsigned short* sb = &lds[(c + 1) & 1][0];
#pragma unroll
            for (int i = 0; i < 4; i++) {
                async16(kc + (size_t)(i * 128 + tid) * 8,
                        sb + (i * 128 + wave * 64) * 8);
                async16(vc + (size_t)(i * 128 + tid) * 8,
                        sb + 4096 + (i * 128 + wave * 64) * 8);
            }
        }

        float4v st[2][4];
#pragma unroll
        for (int qt = 0; qt < 2; qt++)
#pragma unroll
            for (int kt = 0; kt < 4; kt++) {
                st[qt][kt] = __builtin_amdgcn_mfma_f32_16x16x32_bf16(
                    kf[kt][0], qf[qt][0], (float4v){0.f, 0.f, 0.f, 0.f},
                    0, 0, 0);
                st[qt][kt] = __builtin_amdgcn_mfma_f32_16x16x32_bf16(
                    kf[kt][1], qf[qt][1], st[qt][kt], 0, 0, 0);
            }

        // V fragments issue while the softmax VALU below runs
        short8 vf[4][2];
#pragma unroll
        for (int nt = 0; nt < 4; nt++)
#pragma unroll
            for (int kk = 0; kk < 2; kk++)
                vf[nt][kk] = *(const short8*)(lb + 4096
                                              + ((nt * 2 + kk) * 64 + lane) * 8);

#pragma unroll
        for (int qt = 0; qt < 2; qt++) {
            const int q0t = q0w + qt * 16;
            const bool needmask = (kb0 + 63 > q0t);  // uniform per (w,qt,c)
            const int qpos = q0t + l16;
            float p[4][4];
#pragma unroll
            for (int kt = 0; kt < 4; kt++)
#pragma unroll
                for (int r = 0; r < 4; r++) {
                    float x = st[qt][kt][r];
                    if (needmask) {
                        int kpos = kb0 + kt * 16 + quad * 4 + r;
                        x = (kpos <= qpos) ? x : -1e30f;
                    }
                    p[kt][r] = __builtin_amdgcn_exp2f(x);
                    lsa[qt][kt] += p[kt][r];     // 4 parallel chains
                }

            unsigned pk[4][2];
#pragma unroll
            for (int kt = 0; kt < 4; kt++)
#pragma unroll
                for (int j = 0; j < 2; j++)
                    pk[kt][j] = __builtin_amdgcn_perm(
                        fbits_rn(p[kt][2 * j + 1]), fbits_rn(p[kt][2 * j]),
                        0x07060302);
            union { unsigned u[4]; short8 s; } pf[2];
#pragma unroll
            for (int kk = 0; kk < 2; kk++)
#pragma unroll
                for (int pp = 0; pp < 4; pp++)
                    pf[kk].u[pp] = pk[kk * 2 + (pp >> 1)][pp & 1];

#pragma unroll
            for (int nt = 0; nt < 4; nt++) {
                o[qt][nt] = __builtin_amdgcn_mfma_f32_16x16x32_bf16(
                    pf[0].s, vf[nt][0], o[qt][nt], 0, 0, 0);
                o[qt][nt] = __builtin_amdgcn_mfma_f32_16x16x32_bf16(
                    pf[1].s, vf[nt][1], o[qt][nt], 0, 0, 0);
            }
        }
    }

    const int b = bh >> 4, h = bh & 15;
#pragma unroll
    for (int qt = 0; qt < 2; qt++) {
        float l = (lsa[qt][0] + lsa[qt][1]) + (lsa[qt][2] + lsa[qt][3]);
        l += __shfl_xor(l, 16, 64);
        l += __shfl_xor(l, 32, 64);
        const float linv = 1.f / l;
        float lr[4];
#pragma unroll
        for (int r = 0; r < 4; r++) lr[r] = __shfl(linv, quad * 4 + r, 64);
#pragma unroll
        for (int r = 0; r < 4; r++) {
            const int s = q0w + qt * 16 + quad * 4 + r;
            const size_t off = ((size_t)(b * S_LEN + s)) * DMODEL + h * HDIM;
#pragma unroll
            for (int nt = 0; nt < 4; nt++)
                ctx[off + nt * 16 + l16] = f2bf(o[qt][nt][r] * lr[r]);
        }
    }
}

extern "C" void kernel_launch(void* const* d_in, const int* in_sizes, int n_in,
                              void* d_out, int out_size, void* d_ws, size_t ws_size,
                              hipStream_t stream) {
    const float* x     = (const float*)d_in[0];
    const float* Wqkv  = (const float*)d_in[1];
    const float* bqkv  = (const float*)d_in[2];
    const float* Wproj = (const float*)d_in[3];
    const float* bproj = (const float*)d_in[4];
    float* out = (float*)d_out;

    const int M  = 2 * S_LEN;     // 4096
    const int N1 = 3 * DMODEL;    // 3072
    const int K  = DMODEL;        // 1024

    unsigned short* x_bf    = (unsigned short*)d_ws;
    unsigned short* wqkv_t  = x_bf   + (size_t)M * K;
    unsigned short* wproj_t = wqkv_t + (size_t)K * N1;
    unsigned short* q_bf    = wproj_t + (size_t)K * DMODEL;
    unsigned short* kp_bf   = q_bf   + (size_t)M * DMODEL;
    unsigned short* v_bf    = kp_bf  + (size_t)M * DMODEL;
    unsigned short* ctx_bf  = v_bf   + (size_t)M * DMODEL;
    unsigned short* vp_bf   = x_bf;   // alias: x_bf dead after QKV GEMM

    {
        int n4 = (M * K) / 4;
        f32_to_bf16_v4<<<n4 / 256, 256, 0, stream>>>((const float4*)x,
                                                     (ushort4*)x_bf, n4);
    }
    {
        dim3 g(64, 16);
        w_transpose_bf16<<<g, 256, 0, stream>>>(Wqkv, Wproj, wqkv_t, wproj_t);
    }

    dim3 g1(N1 / 128, M / 128);   // 24 x 32
    gemm_qkv_kernel<<<g1, 256, 0, stream>>>(x_bf, wqkv_t, bqkv,
                                            q_bf, kp_bf, v_bf, M, N1, K);

    {
        dim3 g(S_LEN / 64, 2 * NHEAD);  // 32 x 32
        v_pack<<<g, 256, 0, stream>>>(v_bf, vp_bf);
    }

    attn8_kernel<<<1024, 128, 0, stream>>>(q_bf, kp_bf, vp_bf, ctx_bf);

    dim3 g3(DMODEL / 128, M / 64);   // 8 x 64
    gemm_proj_kernel<<<g3, 256, 0, stream>>>(ctx_bf, wproj_t, bproj, out,
                                             M, DMODEL, K);
}

// Round 5
// 184.102 us; speedup vs baseline: 1.0101x; 1.0101x over previous
//
#include <hip/hip_runtime.h>
#include <hip/hip_bf16.h>

// B=2, S=2048, D=1024, H=16, HD=64.  out = proj(attn(qkv(x))), fp32 I/O,
// bf16 MFMA internally.
//
// R16 (attn9 + combine): attention is bound by the LONGEST block's serial
// chunk chain (barrier-synchronized), not aggregate LDS BW: attn6 = 32
// chunks x ~925ns; attn8 doubled per-wave chunk work and regressed exactly
// proportionally.  attn9 splits the chunk (key) range per query-block
// across 2 blocks: 2048 blocks = 32 bh x 32 qb x 2 halves, attn6 geometry
// (256 thr, 4 waves, 16 q/wave).  No running max in this formulation, so
// partials combine additively: each half writes fp32 partial o + lsum;
// combine_kernel sums, normalizes, emits bf16 ctx.  Max chain 32 -> 16
// chunks; 2048 blocks keep ~5/CU resident (LDS-bound) through the tail.

typedef __attribute__((ext_vector_type(8))) short short8;
typedef __attribute__((ext_vector_type(4))) float float4v;

#define S_LEN 2048
#define NHEAD 16
#define HDIM  64
#define DMODEL 1024

__device__ __forceinline__ unsigned short f2bf(float f) {
    union { float f; unsigned u; } v; v.f = f;
    unsigned r = v.u + 0x7FFF + ((v.u >> 16) & 1);   // RNE
    return (unsigned short)(r >> 16);
}

__device__ __forceinline__ unsigned fbits_rn(float f) {  // bits+0x8000: RN pack
    union { float f; unsigned u; } v; v.f = f;
    return v.u + 0x8000u;
}

__device__ __forceinline__ void async16(const void* g, const void* l) {
    __builtin_amdgcn_global_load_lds(
        (const __attribute__((address_space(1))) unsigned int*)g,
        (__attribute__((address_space(3))) unsigned int*)l, 16, 0, 0);
}

// ---------------------------------------------------------------------------
__global__ void f32_to_bf16_v4(const float4* __restrict__ in,
                               ushort4* __restrict__ out, int n4) {
    int i = blockIdx.x * blockDim.x + threadIdx.x;
    if (i < n4) {
        float4 v = in[i];
        ushort4 o;
        o.x = f2bf(v.x); o.y = f2bf(v.y); o.z = f2bf(v.z); o.w = f2bf(v.w);
        out[i] = o;
    }
}

// Both weight matrices, one launch. in[K][N] fp32 -> out[N][K] bf16.
__global__ __launch_bounds__(256) void w_transpose_bf16(
    const float* __restrict__ Wqkv, const float* __restrict__ Wproj,
    unsigned short* __restrict__ outQ, unsigned short* __restrict__ outP) {
    __shared__ float t[64][65];
    const float* in; unsigned short* out; int N, bxl;
    if (blockIdx.x < 48) { in = Wqkv;  out = outQ; N = 3072; bxl = blockIdx.x; }
    else                 { in = Wproj; out = outP; N = 1024; bxl = blockIdx.x - 48; }
    const int K = 1024;
    const int kb = blockIdx.y * 64, nb = bxl * 64;
    const int tid = threadIdx.x;
    const int r0 = tid >> 4, c0 = (tid & 15) * 4;
#pragma unroll
    for (int g = 0; g < 4; g++) {
        float4 v = *(const float4*)(in + (size_t)(kb + g * 16 + r0) * N + nb + c0);
        t[g * 16 + r0][c0 + 0] = v.x; t[g * 16 + r0][c0 + 1] = v.y;
        t[g * 16 + r0][c0 + 2] = v.z; t[g * 16 + r0][c0 + 3] = v.w;
    }
    __syncthreads();
#pragma unroll
    for (int g = 0; g < 4; g++) {
        int n = g * 16 + r0;
        ushort4 o;
        o.x = f2bf(t[c0 + 0][n]); o.y = f2bf(t[c0 + 1][n]);
        o.z = f2bf(t[c0 + 2][n]); o.w = f2bf(t[c0 + 3][n]);
        *(ushort4*)(out + (size_t)(nb + n) * K + kb + c0) = o;
    }
}

// V [bh][s][64] -> Vp [bh][chunk][nt][kk][lane][8]  (fragment-major).
// Fragment semantics (R3-verified): vf[nt][kk] lane(quad,l16), short j:
//   key = (kk*2 + (j>>2))*16 + quad*4 + (j&3),  hd = nt*16 + l16.
__global__ __launch_bounds__(256) void v_pack(
    const unsigned short* __restrict__ V, unsigned short* __restrict__ Vp) {
    __shared__ unsigned short t[64 * 68];
    const int bh = blockIdx.y;
    const int c0 = blockIdx.x;          // 64-key chunk
    const int s0 = c0 * 64;
    const int tid = threadIdx.x;
    const int r = tid >> 2, c4 = tid & 3;
    const size_t base = (size_t)bh * S_LEN * HDIM;
    union { uint4 v[2]; unsigned short u[16]; } d;
    const unsigned short* src = V + base + (size_t)(s0 + r) * HDIM + c4 * 16;
    d.v[0] = *(const uint4*)(src);
    d.v[1] = *(const uint4*)(src + 8);
#pragma unroll
    for (int j = 0; j < 16; j++) t[r * 68 + c4 * 16 + j] = d.u[j];  // t[key][hd]
    __syncthreads();
    // 512 16B pieces, 2 per thread (consecutive lanes -> 32B/thread store)
    unsigned short* outb = Vp + ((size_t)(bh * 32 + c0)) * 4096;
#pragma unroll
    for (int pi = 0; pi < 2; pi++) {
        const int p = tid * 2 + pi;
        const int lane = p & 63, kk = (p >> 6) & 1, nt = p >> 7;
        const int q = lane >> 4, l = lane & 15;
        union { ushort4 v[2]; unsigned short u[8]; } w;
#pragma unroll
        for (int j = 0; j < 8; j++) {
            const int key = (kk * 2 + (j >> 2)) * 16 + q * 4 + (j & 3);
            w.u[j] = t[key * 68 + nt * 16 + l];
        }
        unsigned short* po = outb + ((nt * 2 + kk) * 64 + lane) * 8;
        *(ushort4*)(po) = w.v[0];
        *(ushort4*)(po + 4) = w.v[1];
    }
}

// ---------------------------------------------------------------------------
// QKV GEMM: C[M,3072] = A[M,1024]*Bt[3072,1024]^T + bias.  BK=64 (two 32-k
// half-planes).  Epilogue: pair-packed ds_write_b32 into 128x132 tile, then
// line-coalesced 16B stores: Q/V -> [bh][s][64], K -> Kp fragment-major.
// ---------------------------------------------------------------------------
#define QSCALE 0.18033688f   // 0.125 * log2(e), folded into Q

__global__ __launch_bounds__(256) void gemm_qkv_kernel(
    const unsigned short* __restrict__ A,
    const unsigned short* __restrict__ Bt,
    const float* __restrict__ bias,
    unsigned short* __restrict__ out_q,
    unsigned short* __restrict__ out_kp,
    unsigned short* __restrict__ out_v,
    int M, int N, int K)
{
    __shared__ unsigned short smem[128 * 132];
    unsigned short* As = smem;            // halves at +0, +4096 shorts
    unsigned short* Bs = smem + 8192;

    const int tid  = threadIdx.x;
    const int lane = tid & 63;
    const int wave = tid >> 6;
    const int quad = lane >> 4;
    const int l16  = lane & 15;

    const int m0 = blockIdx.y * 128;
    const int n0 = blockIdx.x * 128;
    const int wm = (wave >> 1) * 64;
    const int wn = (wave & 1) * 64;

    float4v acc[4][4];
#pragma unroll
    for (int i = 0; i < 4; i++)
#pragma unroll
        for (int j = 0; j < 4; j++) acc[i][j] = (float4v){0.f, 0.f, 0.f, 0.f};

    const int srow = lane >> 2;
    const int scol = (lane & 3) * 8;

    for (int k0 = 0; k0 < K; k0 += 64) {
        __syncthreads();
#pragma unroll
        for (int kk = 0; kk < 2; kk++)
#pragma unroll
            for (int it = 0; it < 2; it++) {
                const int rg = it * 64 + wave * 16;
                async16(A  + (size_t)(m0 + rg + srow) * K + k0 + kk * 32 + scol,
                        (const char*)(As + kk * 4096) + rg * 64);
                async16(Bt + (size_t)(n0 + rg + srow) * K + k0 + kk * 32 + scol,
                        (const char*)(Bs + kk * 4096) + rg * 64);
            }
        __syncthreads();

#pragma unroll
        for (int kk = 0; kk < 2; kk++) {
            short8 af[4], bf[4];
#pragma unroll
            for (int mt = 0; mt < 4; mt++)
                af[mt] = *(const short8*)(As + kk * 4096
                                          + (wm + mt * 16 + l16) * 32 + quad * 8);
#pragma unroll
            for (int nt = 0; nt < 4; nt++)
                bf[nt] = *(const short8*)(Bs + kk * 4096
                                          + (wn + nt * 16 + l16) * 32 + quad * 8);
#pragma unroll
            for (int mt = 0; mt < 4; mt++)
#pragma unroll
                for (int nt = 0; nt < 4; nt++)
                    acc[mt][nt] = __builtin_amdgcn_mfma_f32_16x16x32_bf16(
                        af[mt], bf[nt], acc[mt][nt], 0, 0, 0);
        }
    }

    // ---- epilogue: pair-packed b32 writes ----
    __syncthreads();
#pragma unroll
    for (int nt = 0; nt < 4; nt++) {
        const int col = n0 + wn + nt * 16 + l16;
        const float sc = ((col >> 10) == 0) ? QSCALE : 1.0f;
        const float bia = bias[col] * sc;
        const int cold = (wn + nt * 16 + l16) >> 1;
#pragma unroll
        for (int mt = 0; mt < 4; mt++)
#pragma unroll
            for (int r = 0; r < 4; r++) {
                unsigned fb = fbits_rn(acc[mt][nt][r] * sc + bia);
                unsigned fbp = (unsigned)__shfl_xor((int)fb, 1, 64);
                unsigned pd = (l16 & 1)
                    ? __builtin_amdgcn_perm(fb, fbp, 0x07060302)
                    : __builtin_amdgcn_perm(fbp, fb, 0x07060302);
                const int rowl = wm + mt * 16 + quad * 4 + r;
                *((unsigned*)smem + rowl * 66 + cold) = pd;
            }
    }
    __syncthreads();

    // ---- store phase: 16B pieces; K pieces go to fragment-major Kp ----
#pragma unroll
    for (int ps = 0; ps < 8; ps++) {
        const int row = ps * 16 + (tid >> 4);
        const int pc  = tid & 15;
        const int col0 = pc * 8;
        const int cb = n0 + (col0 >> 6) * 64;
        const int part = cb >> 10;
        const int hh = (cb & 1023) >> 6;           // head
        const int gr = m0 + row;
        const int b = gr >> 11, s = gr & 2047;
        const size_t bhI = (size_t)(b * NHEAD + hh);
        const unsigned short* pl = smem + row * 132 + col0;
        uint2 a = *(const uint2*)(pl);
        uint2 bb = *(const uint2*)(pl + 4);
        uint4 w; w.x = a.x; w.y = a.y; w.z = bb.x; w.w = bb.y;
        unsigned short* po;
        if (part == 1) {
            // Kp[bh][chunk=s>>6][kt=(s>>4)&3][h][lane=q*16+(s&15)][8]
            const int hd = col0 & 63;
            const int h = hd >> 5, q = (hd >> 3) & 3;
            po = out_kp + ((((bhI * 32 + (s >> 6)) * 4 + ((s >> 4) & 3)) * 2 + h)
                           * 64 + q * 16 + (s & 15)) * 8;
        } else {
            unsigned short* dst = (part == 0) ? out_q : out_v;
            po = dst + (bhI * S_LEN + s) * HDIM + (col0 & 63);
        }
        *(uint4*)po = w;
    }
}

// ---------------------------------------------------------------------------
// proj GEMM: out[M,1024] fp32 = ctx[M,1024]*Wt^T + bias.  64x128 tile, BK=64.
// ---------------------------------------------------------------------------
__global__ __launch_bounds__(256) void gemm_proj_kernel(
    const unsigned short* __restrict__ A,
    const unsigned short* __restrict__ Bt,
    const float* __restrict__ bias,
    float* __restrict__ out_f,
    int M, int N, int K)
{
    __shared__ unsigned short smem[12288];
    unsigned short* As = smem;               // halves at +0, +2048
    unsigned short* Bs = smem + 4096;        // halves at +0, +4096

    const int tid  = threadIdx.x;
    const int lane = tid & 63;
    const int wave = tid >> 6;
    const int quad = lane >> 4;
    const int l16  = lane & 15;

    const int m0 = blockIdx.y * 64;
    const int n0 = blockIdx.x * 128;
    const int wm = (wave >> 1) * 32;
    const int wn = (wave & 1) * 64;

    float4v acc[2][4];
#pragma unroll
    for (int i = 0; i < 2; i++)
#pragma unroll
        for (int j = 0; j < 4; j++) acc[i][j] = (float4v){0.f, 0.f, 0.f, 0.f};

    const int srow = lane >> 2;
    const int scol = (lane & 3) * 8;

    for (int k0 = 0; k0 < K; k0 += 64) {
        __syncthreads();
#pragma unroll
        for (int kk = 0; kk < 2; kk++) {
            async16(A + (size_t)(m0 + wave * 16 + srow) * K + k0 + kk * 32 + scol,
                    (const char*)(As + kk * 2048) + wave * 1024);
#pragma unroll
            for (int it = 0; it < 2; it++) {
                const int rg = it * 64 + wave * 16;
                async16(Bt + (size_t)(n0 + rg + srow) * K + k0 + kk * 32 + scol,
                        (const char*)(Bs + kk * 4096) + rg * 64);
            }
        }
        __syncthreads();

#pragma unroll
        for (int kk = 0; kk < 2; kk++) {
            short8 af[2], bf[4];
#pragma unroll
            for (int mt = 0; mt < 2; mt++)
                af[mt] = *(const short8*)(As + kk * 2048
                                          + (wm + mt * 16 + l16) * 32 + quad * 8);
#pragma unroll
            for (int nt = 0; nt < 4; nt++)
                bf[nt] = *(const short8*)(Bs + kk * 4096
                                          + (wn + nt * 16 + l16) * 32 + quad * 8);
#pragma unroll
            for (int mt = 0; mt < 2; mt++)
#pragma unroll
                for (int nt = 0; nt < 4; nt++)
                    acc[mt][nt] = __builtin_amdgcn_mfma_f32_16x16x32_bf16(
                        af[mt], bf[nt], acc[mt][nt], 0, 0, 0);
        }
    }

#pragma unroll
    for (int nt = 0; nt < 4; nt++) {
        const int col = n0 + wn + nt * 16 + l16;
        const float bia = bias[col];
#pragma unroll
        for (int mt = 0; mt < 2; mt++) {
            const int rowb = m0 + wm + mt * 16 + quad * 4;
#pragma unroll
            for (int r = 0; r < 4; r++)
                out_f[(size_t)(rowb + r) * N + col] = acc[mt][nt][r] + bia;
        }
    }
}

// ---------------------------------------------------------------------------
// Attention v9: chunk-split flash blocks.  2048 blocks x 256 thr.
// bx&31 = bh (XCD pin); r = 63-(bx>>5): qb = r>>1, half = r&1 (heavy halves
// dispatch first).  Block geometry = attn6: 4 waves x 16 queries.
// half 0 processes chunks [0, h0), half 1 [h0, n) where n = qb+1,
// h0 = (n+1)/2.  No running max -> partials combine additively:
// writes fp32 partial o to op[half][bh][s][64] and lsum to lp[half][bh][s].
// ---------------------------------------------------------------------------
__global__ __launch_bounds__(256) void attn9_kernel(
    const unsigned short* __restrict__ Q,    // [bh][s][64] pre-scaled
    const unsigned short* __restrict__ Kp,   // [bh][32][4][2][64][8]
    const unsigned short* __restrict__ Vp,   // [bh][32][4][2][64][8]
    float* __restrict__ op,                  // [2][32][2048][64] fp32 partial o
    float* __restrict__ lp)                  // [2][32][2048] fp32 partial lsum
{
    __shared__ unsigned short lds[2][8192];  // [buf][K 0..4095 | V 4096..8191]

    const int tid  = threadIdx.x;
    const int lane = tid & 63;
    const int wave = tid >> 6;
    const int quad = lane >> 4;
    const int l16  = lane & 15;

    const int bx = blockIdx.x;
    const int bh = bx & 31;
    const int r_ = 63 - (bx >> 5);           // heavy-first
    const int qb   = r_ >> 1;
    const int half = r_ & 1;
    const int n  = qb + 1;
    const int h0 = (n + 1) >> 1;
    const int cstart = half ? h0 : 0;
    const int cend   = half ? n  : h0;
    const int q0 = qb * 64 + wave * 16;

    const size_t baseQ = (size_t)bh * S_LEN * HDIM;
    const unsigned short* kb_ = Kp + (size_t)bh * 32 * 4096;
    const unsigned short* vb_ = Vp + (size_t)bh * 32 * 4096;

    short8 qf[2];
#pragma unroll
    for (int h = 0; h < 2; h++)
        qf[h] = *(const short8*)(Q + baseQ + (size_t)(q0 + l16) * HDIM
                                 + h * 32 + quad * 8);

    float4v o[4];
#pragma unroll
    for (int nt = 0; nt < 4; nt++) o[nt] = (float4v){0.f, 0.f, 0.f, 0.f};
    float lsa[4] = {0.f, 0.f, 0.f, 0.f};

    if (cstart < cend) {
        // prologue: stage chunk cstart (16 KB: 4 x async16 / thread)
        {
            const unsigned short* kc = kb_ + (size_t)cstart * 4096;
            const unsigned short* vc = vb_ + (size_t)cstart * 4096;
            unsigned short* sb = &lds[cstart & 1][0];
            async16(kc + tid * 8,        sb + wave * 512);
            async16(kc + 2048 + tid * 8, sb + 2048 + wave * 512);
            async16(vc + tid * 8,        sb + 4096 + wave * 512);
            async16(vc + 2048 + tid * 8, sb + 6144 + wave * 512);
        }

        for (int c = cstart; c < cend; c++) {
            __syncthreads();   // drains stage (implicit vmcnt(0)); buf ready
            const unsigned short* lb = &lds[c & 1][0];

            // K fragments: linear conflict-free ds_read_b128
            short8 kf[4][2];
#pragma unroll
            for (int kt = 0; kt < 4; kt++)
#pragma unroll
                for (int h = 0; h < 2; h++)
                    kf[kt][h] = *(const short8*)(lb
                                                 + ((kt * 2 + h) * 64 + lane) * 8);

            // stage chunk c+1 into the other buffer (overlaps compute below)
            if (c + 1 < cend) {
                const unsigned short* kc = kb_ + (size_t)(c + 1) * 4096;
                const unsigned short* vc = vb_ + (size_t)(c + 1) * 4096;
                unsigned short* sb = &lds[(c + 1) & 1][0];
                async16(kc + tid * 8,        sb + wave * 512);
                async16(kc + 2048 + tid * 8, sb + 2048 + wave * 512);
                async16(vc + tid * 8,        sb + 4096 + wave * 512);
                async16(vc + 2048 + tid * 8, sb + 6144 + wave * 512);
            }

            float4v st[4];
#pragma unroll
            for (int kt = 0; kt < 4; kt++) {
                st[kt] = __builtin_amdgcn_mfma_f32_16x16x32_bf16(
                    kf[kt][0], qf[0], (float4v){0.f, 0.f, 0.f, 0.f}, 0, 0, 0);
                st[kt] = __builtin_amdgcn_mfma_f32_16x16x32_bf16(
                    kf[kt][1], qf[1], st[kt], 0, 0, 0);
            }

            // V fragments issue while the softmax VALU below runs
            short8 vf[4][2];
#pragma unroll
            for (int nt = 0; nt < 4; nt++)
#pragma unroll
                for (int kk = 0; kk < 2; kk++)
                    vf[nt][kk] = *(const short8*)(lb + 4096
                                                  + ((nt * 2 + kk) * 64 + lane) * 8);

            const int kb0 = c * 64;
            const bool needmask = (kb0 + 63 > q0);  // uniform per (wave,c)
            const int qpos = q0 + l16;
            float p[4][4];
#pragma unroll
            for (int kt = 0; kt < 4; kt++)
#pragma unroll
                for (int rr = 0; rr < 4; rr++) {
                    float x = st[kt][rr];
                    if (needmask) {
                        int kpos = kb0 + kt * 16 + quad * 4 + rr;
                        x = (kpos <= qpos) ? x : -1e30f;
                    }
                    p[kt][rr] = __builtin_amdgcn_exp2f(x);
                    lsa[kt] += p[kt][rr];     // 4 parallel chains
                }

            unsigned pk[4][2];
#pragma unroll
            for (int kt = 0; kt < 4; kt++)
#pragma unroll
                for (int j = 0; j < 2; j++)
                    pk[kt][j] = __builtin_amdgcn_perm(
                        fbits_rn(p[kt][2 * j + 1]), fbits_rn(p[kt][2 * j]),
                        0x07060302);
            union { unsigned u[4]; short8 s; } pf[2];
#pragma unroll
            for (int kk = 0; kk < 2; kk++)
#pragma unroll
                for (int pp = 0; pp < 4; pp++)
                    pf[kk].u[pp] = pk[kk * 2 + (pp >> 1)][pp & 1];

#pragma unroll
            for (int nt = 0; nt < 4; nt++) {
                o[nt] = __builtin_amdgcn_mfma_f32_16x16x32_bf16(
                    pf[0].s, vf[nt][0], o[nt], 0, 0, 0);
                o[nt] = __builtin_amdgcn_mfma_f32_16x16x32_bf16(
                    pf[1].s, vf[nt][1], o[nt], 0, 0, 0);
            }
        }
    }

    // ---- write fp32 partials (no normalization here) ----
    float l = (lsa[0] + lsa[1]) + (lsa[2] + lsa[3]);
    l += __shfl_xor(l, 16, 64);
    l += __shfl_xor(l, 32, 64);
    // lane l16 (quad 0 suffices) holds lsum for query q0 + l16
    if (lane < 16)
        lp[((size_t)half * 32 + bh) * S_LEN + q0 + l16] = l;

    float* pob = op + (((size_t)half * 32 + bh) * S_LEN) * HDIM;
#pragma unroll
    for (int rr = 0; rr < 4; rr++) {
        const int s = q0 + quad * 4 + rr;
#pragma unroll
        for (int nt = 0; nt < 4; nt++)
            pob[(size_t)s * HDIM + nt * 16 + l16] = o[nt][rr];
    }
}

// ---------------------------------------------------------------------------
// combine: ctx[bh][s][hd] = bf16( (op0+op1) / (lp0+lp1) ).
// 2048 blocks x 256 thr; 8 threads per query (8 hd each, 32B vec loads).
// ---------------------------------------------------------------------------
__global__ __launch_bounds__(256) void combine_kernel(
    const float* __restrict__ op,    // [2][32][2048][64]
    const float* __restrict__ lp,    // [2][32][2048]
    unsigned short* __restrict__ ctx)  // [B, S, H*64]
{
    const int t = blockIdx.x * 256 + threadIdx.x;
    const int qid = t >> 3;              // 0..65535 = bh*2048 + s
    const int hd0 = (t & 7) * 8;
    const size_t NQ = 32 * (size_t)S_LEN;

    const float* p0 = op + (size_t)qid * HDIM + hd0;
    const float* p1 = op + (NQ + qid) * HDIM + hd0;
    float4 a0 = *(const float4*)(p0);
    float4 a1 = *(const float4*)(p0 + 4);
    float4 b0 = *(const float4*)(p1);
    float4 b1 = *(const float4*)(p1 + 4);
    const float linv = 1.f / (lp[qid] + lp[NQ + qid]);

    union { ushort4 v[2]; uint4 q; } w;
    w.v[0].x = f2bf((a0.x + b0.x) * linv);
    w.v[0].y = f2bf((a0.y + b0.y) * linv);
    w.v[0].z = f2bf((a0.z + b0.z) * linv);
    w.v[0].w = f2bf((a0.w + b0.w) * linv);
    w.v[1].x = f2bf((a1.x + b1.x) * linv);
    w.v[1].y = f2bf((a1.y + b1.y) * linv);
    w.v[1].z = f2bf((a1.z + b1.z) * linv);
    w.v[1].w = f2bf((a1.w + b1.w) * linv);

    const int bh = qid >> 11, s = qid & 2047;
    const int b = bh >> 4, h = bh & 15;
    *(uint4*)(ctx + ((size_t)(b * S_LEN + s)) * DMODEL + h * HDIM + hd0) = w.q;
}

extern "C" void kernel_launch(void* const* d_in, const int* in_sizes, int n_in,
                              void* d_out, int out_size, void* d_ws, size_t ws_size,
                              hipStream_t stream) {
    const float* x     = (const float*)d_in[0];
    const float* Wqkv  = (const float*)d_in[1];
    const float* bqkv  = (const float*)d_in[2];
    const float* Wproj = (const float*)d_in[3];
    const float* bproj = (const float*)d_in[4];
    float* out = (float*)d_out;

    const int M  = 2 * S_LEN;     // 4096
    const int N1 = 3 * DMODEL;    // 3072
    const int K  = DMODEL;        // 1024

    unsigned short* x_bf    = (unsigned short*)d_ws;
    unsigned short* wqkv_t  = x_bf   + (size_t)M * K;
    unsigned short* wproj_t = wqkv_t + (size_t)K * N1;
    unsigned short* q_bf    = wproj_t + (size_t)K * DMODEL;
    unsigned short* kp_bf   = q_bf   + (size_t)M * DMODEL;
    unsigned short* v_bf    = kp_bf  + (size_t)M * DMODEL;
    unsigned short* ctx_bf  = v_bf   + (size_t)M * DMODEL;
    unsigned short* vp_bf   = x_bf;   // alias: x_bf dead after QKV GEMM
    float* op = (float*)(ctx_bf + (size_t)M * DMODEL);   // 32 MB fp32 partials
    float* lp = op + (size_t)2 * 32 * S_LEN * HDIM;      // 0.5 MB

    {
        int n4 = (M * K) / 4;
        f32_to_bf16_v4<<<n4 / 256, 256, 0, stream>>>((const float4*)x,
                                                     (ushort4*)x_bf, n4);
    }
    {
        dim3 g(64, 16);
        w_transpose_bf16<<<g, 256, 0, stream>>>(Wqkv, Wproj, wqkv_t, wproj_t);
    }

    dim3 g1(N1 / 128, M / 128);   // 24 x 32
    gemm_qkv_kernel<<<g1, 256, 0, stream>>>(x_bf, wqkv_t, bqkv,
                                            q_bf, kp_bf, v_bf, M, N1, K);

    {
        dim3 g(S_LEN / 64, 2 * NHEAD);  // 32 x 32
        v_pack<<<g, 256, 0, stream>>>(v_bf, vp_bf);
    }

    attn9_kernel<<<2048, 256, 0, stream>>>(q_bf, kp_bf, vp_bf, op, lp);
    combine_kernel<<<2048, 256, 0, stream>>>(op, lp, ctx_bf);

    dim3 g3(DMODEL / 128, M / 64);   // 8 x 64
    gemm_proj_kernel<<<g3, 256, 0, stream>>>(ctx_bf, wproj_t, bproj, out,
                                             M, DMODEL, K);
}

// Round 6
// 169.415 us; speedup vs baseline: 1.0977x; 1.0867x over previous
//
#include <hip/hip_runtime.h>
#include <hip/hip_bf16.h>

// B=2, S=2048, D=1024, H=16, HD=64.  out = proj(attn(qkv(x))), fp32 I/O,
// bf16 MFMA internally.
//
// R17 = R12 (attn6, best measured: 172.3 us total) + v_pack folded into the
// QKV epilogue.  R16's chunk-split attn9 regressed (partial-o fp32 traffic
// ~75 MB + extra launch > chain win) -> reverted.  R16's profile surfaced
// gemm_qkv (42.4 us) as the largest kernel; its epilogue smem tile already
// holds the s x hd data for 2 chunks x 2 heads of V per block, so the
// store phase now emits Vp fragment-major directly (8 u16 gathers per 16B
// piece), exactly like it already does for Kp.  v_pack kernel + its ~34 MB
// of intermediate V traffic are deleted.

typedef __attribute__((ext_vector_type(8))) short short8;
typedef __attribute__((ext_vector_type(4))) float float4v;

#define S_LEN 2048
#define NHEAD 16
#define HDIM  64
#define DMODEL 1024

__device__ __forceinline__ unsigned short f2bf(float f) {
    union { float f; unsigned u; } v; v.f = f;
    unsigned r = v.u + 0x7FFF + ((v.u >> 16) & 1);   // RNE
    return (unsigned short)(r >> 16);
}

__device__ __forceinline__ unsigned fbits_rn(float f) {  // bits+0x8000: RN pack
    union { float f; unsigned u; } v; v.f = f;
    return v.u + 0x8000u;
}

__device__ __forceinline__ void async16(const void* g, const void* l) {
    __builtin_amdgcn_global_load_lds(
        (const __attribute__((address_space(1))) unsigned int*)g,
        (__attribute__((address_space(3))) unsigned int*)l, 16, 0, 0);
}

// ---------------------------------------------------------------------------
__global__ void f32_to_bf16_v4(const float4* __restrict__ in,
                               ushort4* __restrict__ out, int n4) {
    int i = blockIdx.x * blockDim.x + threadIdx.x;
    if (i < n4) {
        float4 v = in[i];
        ushort4 o;
        o.x = f2bf(v.x); o.y = f2bf(v.y); o.z = f2bf(v.z); o.w = f2bf(v.w);
        out[i] = o;
    }
}

// Both weight matrices, one launch. in[K][N] fp32 -> out[N][K] bf16.
__global__ __launch_bounds__(256) void w_transpose_bf16(
    const float* __restrict__ Wqkv, const float* __restrict__ Wproj,
    unsigned short* __restrict__ outQ, unsigned short* __restrict__ outP) {
    __shared__ float t[64][65];
    const float* in; unsigned short* out; int N, bxl;
    if (blockIdx.x < 48) { in = Wqkv;  out = outQ; N = 3072; bxl = blockIdx.x; }
    else                 { in = Wproj; out = outP; N = 1024; bxl = blockIdx.x - 48; }
    const int K = 1024;
    const int kb = blockIdx.y * 64, nb = bxl * 64;
    const int tid = threadIdx.x;
    const int r0 = tid >> 4, c0 = (tid & 15) * 4;
#pragma unroll
    for (int g = 0; g < 4; g++) {
        float4 v = *(const float4*)(in + (size_t)(kb + g * 16 + r0) * N + nb + c0);
        t[g * 16 + r0][c0 + 0] = v.x; t[g * 16 + r0][c0 + 1] = v.y;
        t[g * 16 + r0][c0 + 2] = v.z; t[g * 16 + r0][c0 + 3] = v.w;
    }
    __syncthreads();
#pragma unroll
    for (int g = 0; g < 4; g++) {
        int n = g * 16 + r0;
        ushort4 o;
        o.x = f2bf(t[c0 + 0][n]); o.y = f2bf(t[c0 + 1][n]);
        o.z = f2bf(t[c0 + 2][n]); o.w = f2bf(t[c0 + 3][n]);
        *(ushort4*)(out + (size_t)(nb + n) * K + kb + c0) = o;
    }
}

// ---------------------------------------------------------------------------
// QKV GEMM: C[M,3072] = A[M,1024]*Bt[3072,1024]^T + bias.  BK=64 (two 32-k
// half-planes).  Epilogue: pair-packed ds_write_b32 into 128x132 tile, then
// line-coalesced 16B stores: Q -> [bh][s][64], K -> Kp fragment-major,
// V -> Vp fragment-major (v_pack folded in: 8 u16 gathers per piece).
// Vp semantics (R3-verified): piece (ch,nt,kk,lane=q*16+l), short j holds
//   key = (kk*2 + (j>>2))*16 + q*4 + (j&3),  hd = nt*16 + l.
// ---------------------------------------------------------------------------
#define QSCALE 0.18033688f   // 0.125 * log2(e), folded into Q

__global__ __launch_bounds__(256) void gemm_qkv_kernel(
    const unsigned short* __restrict__ A,
    const unsigned short* __restrict__ Bt,
    const float* __restrict__ bias,
    unsigned short* __restrict__ out_q,
    unsigned short* __restrict__ out_kp,
    unsigned short* __restrict__ out_vp,
    int M, int N, int K)
{
    __shared__ unsigned short smem[128 * 132];
    unsigned short* As = smem;            // halves at +0, +4096 shorts
    unsigned short* Bs = smem + 8192;

    const int tid  = threadIdx.x;
    const int lane = tid & 63;
    const int wave = tid >> 6;
    const int quad = lane >> 4;
    const int l16  = lane & 15;

    const int m0 = blockIdx.y * 128;
    const int n0 = blockIdx.x * 128;
    const int wm = (wave >> 1) * 64;
    const int wn = (wave & 1) * 64;

    float4v acc[4][4];
#pragma unroll
    for (int i = 0; i < 4; i++)
#pragma unroll
        for (int j = 0; j < 4; j++) acc[i][j] = (float4v){0.f, 0.f, 0.f, 0.f};

    const int srow = lane >> 2;
    const int scol = (lane & 3) * 8;

    for (int k0 = 0; k0 < K; k0 += 64) {
        __syncthreads();
#pragma unroll
        for (int kk = 0; kk < 2; kk++)
#pragma unroll
            for (int it = 0; it < 2; it++) {
                const int rg = it * 64 + wave * 16;
                async16(A  + (size_t)(m0 + rg + srow) * K + k0 + kk * 32 + scol,
                        (const char*)(As + kk * 4096) + rg * 64);
                async16(Bt + (size_t)(n0 + rg + srow) * K + k0 + kk * 32 + scol,
                        (const char*)(Bs + kk * 4096) + rg * 64);
            }
        __syncthreads();

#pragma unroll
        for (int kk = 0; kk < 2; kk++) {
            short8 af[4], bf[4];
#pragma unroll
            for (int mt = 0; mt < 4; mt++)
                af[mt] = *(const short8*)(As + kk * 4096
                                          + (wm + mt * 16 + l16) * 32 + quad * 8);
#pragma unroll
            for (int nt = 0; nt < 4; nt++)
                bf[nt] = *(const short8*)(Bs + kk * 4096
                                          + (wn + nt * 16 + l16) * 32 + quad * 8);
#pragma unroll
            for (int mt = 0; mt < 4; mt++)
#pragma unroll
                for (int nt = 0; nt < 4; nt++)
                    acc[mt][nt] = __builtin_amdgcn_mfma_f32_16x16x32_bf16(
                        af[mt], bf[nt], acc[mt][nt], 0, 0, 0);
        }
    }

    // ---- epilogue: pair-packed b32 writes ----
    __syncthreads();
#pragma unroll
    for (int nt = 0; nt < 4; nt++) {
        const int col = n0 + wn + nt * 16 + l16;
        const float sc = ((col >> 10) == 0) ? QSCALE : 1.0f;
        const float bia = bias[col] * sc;
        const int cold = (wn + nt * 16 + l16) >> 1;
#pragma unroll
        for (int mt = 0; mt < 4; mt++)
#pragma unroll
            for (int r = 0; r < 4; r++) {
                unsigned fb = fbits_rn(acc[mt][nt][r] * sc + bia);
                unsigned fbp = (unsigned)__shfl_xor((int)fb, 1, 64);
                unsigned pd = (l16 & 1)
                    ? __builtin_amdgcn_perm(fb, fbp, 0x07060302)
                    : __builtin_amdgcn_perm(fbp, fb, 0x07060302);
                const int rowl = wm + mt * 16 + quad * 4 + r;
                *((unsigned*)smem + rowl * 66 + cold) = pd;
            }
    }
    __syncthreads();

    // ---- store phase: 16B pieces.  Q: [bh][s][64]; K: Kp fragment-major;
    //      V: Vp fragment-major (gathered). ----
#pragma unroll
    for (int ps = 0; ps < 8; ps++) {
        const int row = ps * 16 + (tid >> 4);
        const int pc  = tid & 15;
        const int col0 = pc * 8;
        const int cb = n0 + (col0 >> 6) * 64;
        const int part = cb >> 10;
        const int hh = (cb & 1023) >> 6;           // head
        const int gr = m0 + row;
        const int b = gr >> 11, s = gr & 2047;
        const size_t bhI = (size_t)(b * NHEAD + hh);
        if (part == 2) {
            // Vp piece: (cl=ps>>2, nt=ps&3, kk=(pc>>2)&1, q=pc&3, l=tid>>4)
            const int l2  = tid >> 4;
            const int q2  = pc & 3;
            const int kk2 = (pc >> 2) & 1;
            const int nt2 = ps & 3;
            const int colb = (pc >> 3) * 64 + nt2 * 16 + l2;
            const int rowb = (ps >> 2) * 64;
            union { unsigned short u[8]; uint4 q; } wv;
#pragma unroll
            for (int j = 0; j < 8; j++) {
                const int key = (kk2 * 2 + (j >> 2)) * 16 + q2 * 4 + (j & 3);
                wv.u[j] = smem[(rowb + key) * 132 + colb];
            }
            unsigned short* po = out_vp
                + ((((bhI * 32 + (s >> 6)) * 4 + nt2) * 2 + kk2) * 64
                   + q2 * 16 + l2) * 8;
            *(uint4*)po = wv.q;
        } else {
            const unsigned short* pl = smem + row * 132 + col0;
            uint2 a = *(const uint2*)(pl);
            uint2 bb = *(const uint2*)(pl + 4);
            uint4 w; w.x = a.x; w.y = a.y; w.z = bb.x; w.w = bb.y;
            unsigned short* po;
            if (part == 1) {
                // Kp[bh][chunk=s>>6][kt=(s>>4)&3][h][lane=q*16+(s&15)][8]
                const int hd = col0 & 63;
                const int h = hd >> 5, q = (hd >> 3) & 3;
                po = out_kp + ((((bhI * 32 + (s >> 6)) * 4 + ((s >> 4) & 3)) * 2
                                + h) * 64 + q * 16 + (s & 15)) * 8;
            } else {
                po = out_q + (bhI * S_LEN + s) * HDIM + (col0 & 63);
            }
            *(uint4*)po = w;
        }
    }
}

// ---------------------------------------------------------------------------
// proj GEMM: out[M,1024] fp32 = ctx[M,1024]*Wt^T + bias.  64x128 tile, BK=64.
// ---------------------------------------------------------------------------
__global__ __launch_bounds__(256) void gemm_proj_kernel(
    const unsigned short* __restrict__ A,
    const unsigned short* __restrict__ Bt,
    const float* __restrict__ bias,
    float* __restrict__ out_f,
    int M, int N, int K)
{
    __shared__ unsigned short smem[12288];
    unsigned short* As = smem;               // halves at +0, +2048
    unsigned short* Bs = smem + 4096;        // halves at +0, +4096

    const int tid  = threadIdx.x;
    const int lane = tid & 63;
    const int wave = tid >> 6;
    const int quad = lane >> 4;
    const int l16  = lane & 15;

    const int m0 = blockIdx.y * 64;
    const int n0 = blockIdx.x * 128;
    const int wm = (wave >> 1) * 32;
    const int wn = (wave & 1) * 64;

    float4v acc[2][4];
#pragma unroll
    for (int i = 0; i < 2; i++)
#pragma unroll
        for (int j = 0; j < 4; j++) acc[i][j] = (float4v){0.f, 0.f, 0.f, 0.f};

    const int srow = lane >> 2;
    const int scol = (lane & 3) * 8;

    for (int k0 = 0; k0 < K; k0 += 64) {
        __syncthreads();
#pragma unroll
        for (int kk = 0; kk < 2; kk++) {
            async16(A + (size_t)(m0 + wave * 16 + srow) * K + k0 + kk * 32 + scol,
                    (const char*)(As + kk * 2048) + wave * 1024);
#pragma unroll
            for (int it = 0; it < 2; it++) {
                const int rg = it * 64 + wave * 16;
                async16(Bt + (size_t)(n0 + rg + srow) * K + k0 + kk * 32 + scol,
                        (const char*)(Bs + kk * 4096) + rg * 64);
            }
        }
        __syncthreads();

#pragma unroll
        for (int kk = 0; kk < 2; kk++) {
            short8 af[2], bf[4];
#pragma unroll
            for (int mt = 0; mt < 2; mt++)
                af[mt] = *(const short8*)(As + kk * 2048
                                          + (wm + mt * 16 + l16) * 32 + quad * 8);
#pragma unroll
            for (int nt = 0; nt < 4; nt++)
                bf[nt] = *(const short8*)(Bs + kk * 4096
                                          + (wn + nt * 16 + l16) * 32 + quad * 8);
#pragma unroll
            for (int mt = 0; mt < 2; mt++)
#pragma unroll
                for (int nt = 0; nt < 4; nt++)
                    acc[mt][nt] = __builtin_amdgcn_mfma_f32_16x16x32_bf16(
                        af[mt], bf[nt], acc[mt][nt], 0, 0, 0);
        }
    }

#pragma unroll
    for (int nt = 0; nt < 4; nt++) {
        const int col = n0 + wn + nt * 16 + l16;
        const float bia = bias[col];
#pragma unroll
        for (int mt = 0; mt < 2; mt++) {
            const int rowb = m0 + wm + mt * 16 + quad * 4;
#pragma unroll
            for (int r = 0; r < 4; r++)
                out_f[(size_t)(rowb + r) * N + col] = acc[mt][nt][r] + bia;
        }
    }
}

// ---------------------------------------------------------------------------
// Attention v6 (R12, best measured): block-shared LDS staging.  1024 blocks
// x 256 thr (4 waves, 16 queries each; all 4 waves consume the SAME K/V
// chunk).  Per chunk the block stages K(8KB)+V(8KB) once into LDS via
// global_load_lds (double-buffered: 2 x 16 KB), then each wave does linear
// conflict-free ds_read_b128 fragment loads.  Stage of chunk c+1 issues
// before the MFMA/softmax of chunk c and drains at the next barrier.
// bh = bx&31 pins heads to XCDs; qb = 31-(bx>>5) dispatches heavy first.
// ---------------------------------------------------------------------------
__global__ __launch_bounds__(256) void attn6_kernel(
    const unsigned short* __restrict__ Q,    // [bh][s][64] pre-scaled
    const unsigned short* __restrict__ Kp,   // [bh][32][4][2][64][8]
    const unsigned short* __restrict__ Vp,   // [bh][32][4][2][64][8]
    unsigned short* __restrict__ ctx)        // [B, S, H*64]
{
    __shared__ unsigned short lds[2][8192];  // [buf][K 0..4095 | V 4096..8191]

    const int tid  = threadIdx.x;
    const int lane = tid & 63;
    const int wave = tid >> 6;
    const int quad = lane >> 4;
    const int l16  = lane & 15;

    const int bx = blockIdx.x;
    const int bh = bx & 31;
    const int qb = 31 - (bx >> 5);
    const int q0 = qb * 64 + wave * 16;
    const int nch = qb + 1;

    const size_t baseQ = (size_t)bh * S_LEN * HDIM;
    const unsigned short* kb_ = Kp + (size_t)bh * 32 * 4096;
    const unsigned short* vb_ = Vp + (size_t)bh * 32 * 4096;

    short8 qf[2];
#pragma unroll
    for (int h = 0; h < 2; h++)
        qf[h] = *(const short8*)(Q + baseQ + (size_t)(q0 + l16) * HDIM
                                 + h * 32 + quad * 8);

    float4v o[4];
#pragma unroll
    for (int nt = 0; nt < 4; nt++) o[nt] = (float4v){0.f, 0.f, 0.f, 0.f};
    float lsa[4] = {0.f, 0.f, 0.f, 0.f};

    // prologue: stage chunk 0 into buffer 0 (16 KB: 4 x async16 / thread)
    {
        unsigned short* sb = &lds[0][0];
        async16(kb_ + tid * 8,        sb + wave * 512);
        async16(kb_ + 2048 + tid * 8, sb + 2048 + wave * 512);
        async16(vb_ + tid * 8,        sb + 4096 + wave * 512);
        async16(vb_ + 2048 + tid * 8, sb + 6144 + wave * 512);
    }

    for (int c = 0; c < nch; c++) {
        __syncthreads();   // drains this wave's stage (implicit vmcnt(0));
                           // all waves' staged chunk c visible; buf c+1&1 free
        const unsigned short* lb = &lds[c & 1][0];

        // K fragments: linear conflict-free ds_read_b128
        short8 kf[4][2];
#pragma unroll
        for (int kt = 0; kt < 4; kt++)
#pragma unroll
            for (int h = 0; h < 2; h++)
                kf[kt][h] = *(const short8*)(lb + ((kt * 2 + h) * 64 + lane) * 8);

        // stage chunk c+1 into the other buffer (overlaps compute below)
        if (c + 1 < nch) {
            const unsigned short* kc = kb_ + (size_t)(c + 1) * 4096;
            const unsigned short* vc = vb_ + (size_t)(c + 1) * 4096;
            unsigned short* sb = &lds[(c + 1) & 1][0];
            async16(kc + tid * 8,        sb + wave * 512);
            async16(kc + 2048 + tid * 8, sb + 2048 + wave * 512);
            async16(vc + tid * 8,        sb + 4096 + wave * 512);
            async16(vc + 2048 + tid * 8, sb + 6144 + wave * 512);
        }

        float4v st[4];
#pragma unroll
        for (int kt = 0; kt < 4; kt++) {
            st[kt] = __builtin_amdgcn_mfma_f32_16x16x32_bf16(
                kf[kt][0], qf[0], (float4v){0.f, 0.f, 0.f, 0.f}, 0, 0, 0);
            st[kt] = __builtin_amdgcn_mfma_f32_16x16x32_bf16(
                kf[kt][1], qf[1], st[kt], 0, 0, 0);
        }

        // V fragments issue while the softmax VALU below runs
        short8 vf[4][2];
#pragma unroll
        for (int nt = 0; nt < 4; nt++)
#pragma unroll
            for (int kk = 0; kk < 2; kk++)
                vf[nt][kk] = *(const short8*)(lb + 4096
                                              + ((nt * 2 + kk) * 64 + lane) * 8);

        const bool lastc = (c == nch - 1);
        const int kb0 = c * 64;
        const int qpos = q0 + l16;
        float p[4][4];
#pragma unroll
        for (int kt = 0; kt < 4; kt++)
#pragma unroll
            for (int r = 0; r < 4; r++) {
                float x = st[kt][r];
                if (lastc) {
                    int kpos = kb0 + kt * 16 + quad * 4 + r;
                    x = (kpos <= qpos) ? x : -1e30f;
                }
                p[kt][r] = __builtin_amdgcn_exp2f(x);
                lsa[kt] += p[kt][r];     // 4 parallel chains
            }

        unsigned pk[4][2];
#pragma unroll
        for (int kt = 0; kt < 4; kt++)
#pragma unroll
            for (int j = 0; j < 2; j++)
                pk[kt][j] = __builtin_amdgcn_perm(
                    fbits_rn(p[kt][2 * j + 1]), fbits_rn(p[kt][2 * j]),
                    0x07060302);
        union { unsigned u[4]; short8 s; } pf[2];
#pragma unroll
        for (int kk = 0; kk < 2; kk++)
#pragma unroll
            for (int pp = 0; pp < 4; pp++)
                pf[kk].u[pp] = pk[kk * 2 + (pp >> 1)][pp & 1];

#pragma unroll
        for (int nt = 0; nt < 4; nt++) {
            o[nt] = __builtin_amdgcn_mfma_f32_16x16x32_bf16(
                pf[0].s, vf[nt][0], o[nt], 0, 0, 0);
            o[nt] = __builtin_amdgcn_mfma_f32_16x16x32_bf16(
                pf[1].s, vf[nt][1], o[nt], 0, 0, 0);
        }
    }

    float l = (lsa[0] + lsa[1]) + (lsa[2] + lsa[3]);
    l += __shfl_xor(l, 16, 64);
    l += __shfl_xor(l, 32, 64);
    const float linv = 1.f / l;
    float lr[4];
#pragma unroll
    for (int r = 0; r < 4; r++) lr[r] = __shfl(linv, quad * 4 + r, 64);

    const int b = bh >> 4, h = bh & 15;
#pragma unroll
    for (int r = 0; r < 4; r++) {
        const int s = q0 + quad * 4 + r;
        const size_t off = ((size_t)(b * S_LEN + s)) * DMODEL + h * HDIM;
#pragma unroll
        for (int nt = 0; nt < 4; nt++)
            ctx[off + nt * 16 + l16] = f2bf(o[nt][r] * lr[r]);
    }
}

extern "C" void kernel_launch(void* const* d_in, const int* in_sizes, int n_in,
                              void* d_out, int out_size, void* d_ws, size_t ws_size,
                              hipStream_t stream) {
    const float* x     = (const float*)d_in[0];
    const float* Wqkv  = (const float*)d_in[1];
    const float* bqkv  = (const float*)d_in[2];
    const float* Wproj = (const float*)d_in[3];
    const float* bproj = (const float*)d_in[4];
    float* out = (float*)d_out;

    const int M  = 2 * S_LEN;     // 4096
    const int N1 = 3 * DMODEL;    // 3072
    const int K  = DMODEL;        // 1024

    unsigned short* x_bf    = (unsigned short*)d_ws;
    unsigned short* wqkv_t  = x_bf   + (size_t)M * K;
    unsigned short* wproj_t = wqkv_t + (size_t)K * N1;
    unsigned short* q_bf    = wproj_t + (size_t)K * DMODEL;
    unsigned short* kp_bf   = q_bf   + (size_t)M * DMODEL;
    unsigned short* vp_bf   = kp_bf  + (size_t)M * DMODEL;  // Vp fragment-major
    unsigned short* ctx_bf  = vp_bf  + (size_t)M * DMODEL;

    {
        int n4 = (M * K) / 4;
        f32_to_bf16_v4<<<n4 / 256, 256, 0, stream>>>((const float4*)x,
                                                     (ushort4*)x_bf, n4);
    }
    {
        dim3 g(64, 16);
        w_transpose_bf16<<<g, 256, 0, stream>>>(Wqkv, Wproj, wqkv_t, wproj_t);
    }

    dim3 g1(N1 / 128, M / 128);   // 24 x 32
    gemm_qkv_kernel<<<g1, 256, 0, stream>>>(x_bf, wqkv_t, bqkv,
                                            q_bf, kp_bf, vp_bf, M, N1, K);

    attn6_kernel<<<1024, 256, 0, stream>>>(q_bf, kp_bf, vp_bf, ctx_bf);

    dim3 g3(DMODEL / 128, M / 64);   // 8 x 64
    gemm_proj_kernel<<<g3, 256, 0, stream>>>(ctx_bf, wproj_t, bproj, out,
                                             M, DMODEL, K);
}